// Round 4
// baseline (129.851 us; speedup 1.0000x reference)
//
#include <hip/hip_runtime.h>
#include <stdint.h>

#define NN 4096
#define NB 32          // NN / 128
#define BK 32          // K-step (one 16x16x32 MFMA per step)

// trimm grid: [0,1704) K-split units over lower tiles (heavy-d first, <=16
// K-steps each), [1704,2200) strict-upper zero tiles.
#define NUNITS 1704
#define ZBASE 1704
#define TGRID 2200

// prep grid: [0,4096) A rows, [4096,8192) B 64x64 subtiles,
// [8192,8598) zero-init for multi-unit C tiles (d>=4)
#define NMULTI 406
#define PGRID 8598

typedef __bf16 bf16x8 __attribute__((ext_vector_type(8)));
typedef float f32x4 __attribute__((ext_vector_type(4)));
typedef unsigned short ushort8 __attribute__((ext_vector_type(8)));

// RTNE fp32 -> bf16
__device__ __forceinline__ unsigned short f2bf(float x) {
    union { float f; unsigned int u; } v; v.f = x;
    unsigned int u = v.u;
    u += 0x7fffu + ((u >> 16) & 1u);
    return (unsigned short)(u >> 16);
}

// async global->LDS, 16B per lane; LDS dest is wave-uniform base + lane*16
#define GLOAD16(g, l) __builtin_amdgcn_global_load_lds( \
    (const __attribute__((address_space(1))) unsigned int*)(g), \
    (__attribute__((address_space(3))) unsigned int*)(l), 16, 0, 0)

// ---- fused prep: A lower-prefix convert, B lower transpose-convert, C zero ----
__global__ __launch_bounds__(256) void prep(const float* __restrict__ A,
                                            const float* __restrict__ B,
                                            unsigned short* __restrict__ Ab,
                                            unsigned short* __restrict__ Bt,
                                            float* __restrict__ C) {
    __shared__ float tile[64][65];
    int bid = blockIdx.x;
    int tid = threadIdx.x;

    if (bid < 4096) {
        // A row i: convert fp32 prefix [0, ((i>>7)+1)*128) to bf16
        int i = bid;
        int nslots = (((i >> 7) + 1) * 128) >> 3;   // 8 floats per slot
        const float4* src = reinterpret_cast<const float4*>(A + (size_t)i * NN);
        unsigned short* dst = Ab + (size_t)i * NN;
        for (int p = tid; p < nslots; p += 256) {
            float4 x0 = src[p * 2], x1 = src[p * 2 + 1];
            ushort8 o;
            o[0] = f2bf(x0.x); o[1] = f2bf(x0.y); o[2] = f2bf(x0.z); o[3] = f2bf(x0.w);
            o[4] = f2bf(x1.x); o[5] = f2bf(x1.y); o[6] = f2bf(x1.z); o[7] = f2bf(x1.w);
            *reinterpret_cast<ushort8*>(dst + p * 8) = o;
        }
        return;
    }
    if (bid < 8192) {
        // B 64x64 subtile transpose: needed iff k64 >= (n64 & ~1)  (128-tile lower superset)
        int s = bid - 4096;
        int n64 = s >> 6, k64 = s & 63;
        if (k64 < (n64 & ~1)) return;
        int n0 = n64 * 64, k0 = k64 * 64;
        int tx = tid & 63, ty = tid >> 6;
#pragma unroll
        for (int r = 0; r < 16; ++r) {
            int k = ty + r * 4;
            tile[k][tx] = B[(size_t)(k0 + k) * NN + n0 + tx];
        }
        __syncthreads();
#pragma unroll
        for (int r = 0; r < 16; ++r) {
            int n = ty + r * 4;
            Bt[(size_t)(n0 + n) * NN + k0 + tx] = f2bf(tile[tx][n]);
        }
        return;
    }
    // zero-init multi-unit C tile (atomicAdd targets; re-zeroed every call)
    {
        int z = bid - 8192;  // 0..405, d descending 31..4
        int d = 31, bi, bj;
        for (;;) {
            int cnt = NB - d;
            if (z < cnt) { bj = z; bi = z + d; break; }
            z -= cnt; --d;
        }
        float4 zf = make_float4(0.f, 0.f, 0.f, 0.f);
        float4* cp = reinterpret_cast<float4*>(C + (size_t)bi * 128 * NN + (size_t)bj * 128);
#pragma unroll
        for (int i2 = 0; i2 < 16; ++i2) {
            int slot = tid + i2 * 256;
            int row = slot >> 5, c4 = slot & 31;
            cp[(size_t)row * (NN / 4) + c4] = zf;
        }
    }
}

// ---- triangular GEMM, uniform fine split-K, double-buffered pipeline ----
__global__ __launch_bounds__(256) void trimm(const unsigned short* __restrict__ Ab,
                                             const unsigned short* __restrict__ Bt,
                                             float* __restrict__ C) {
    int bid = blockIdx.x;
    int tid = threadIdx.x;
    int lane = tid & 63;
    int w = tid >> 6;

    int bi, bj;
    int k_lo, k_hi;
    bool multi;

    if (bid >= ZBASE) {
        // strict upper tile: zero-fill 128x128
        int t = bid - ZBASE;
        int r = 0, cnt = NB - 1;
        while (t >= cnt) { t -= cnt; ++r; --cnt; }
        bi = r; bj = r + 1 + t;
        float4 z = make_float4(0.f, 0.f, 0.f, 0.f);
        float4* cp = reinterpret_cast<float4*>(C + (size_t)bi * 128 * NN + (size_t)bj * 128);
#pragma unroll
        for (int i2 = 0; i2 < 16; ++i2) {
            int slot = tid + i2 * 256;
            int row = slot >> 5, c4 = slot & 31;
            cp[(size_t)row * (NN / 4) + c4] = z;
        }
        return;
    }
    {
        // unit decode: d descending from 31; nu(d)=ceil((d+1)/4) units/tile
        int r = bid, d = 31, nu;
        for (;;) {
            nu = (d + 4) >> 2;
            int cnt = (NB - d) * nu;
            if (r < cnt) break;
            r -= cnt; --d;
        }
        int t = r / nu;
        int u = r - t * nu;
        bj = t; bi = t + d;
        multi = (nu > 1);
        int klt = bj * 128, kht = (bi + 1) * 128;
        k_lo = klt + u * 512;
        k_hi = k_lo + 512 < kht ? k_lo + 512 : kht;
    }

    __shared__ unsigned short As[2][128 * BK];
    __shared__ unsigned short Bs[2][128 * BK];

    int wr = w >> 1, wc = w & 1;

    int srow = w * 32 + (lane >> 2);
    int skoff = (lane & 3) * 8;
    const unsigned short* gA0 = Ab + (size_t)(bi * 128 + srow) * NN + skoff;
    const unsigned short* gA1 = gA0 + (size_t)16 * NN;
    const unsigned short* gB0 = Bt + (size_t)(bj * 128 + srow) * NN + skoff;
    const unsigned short* gB1 = gB0 + (size_t)16 * NN;

    f32x4 acc[4][4];
#pragma unroll
    for (int mi = 0; mi < 4; ++mi)
#pragma unroll
        for (int ni = 0; ni < 4; ++ni)
            acc[mi][ni] = (f32x4){0.f, 0.f, 0.f, 0.f};

    int arow = wr * 64 + (lane & 15);
    int brow = wc * 64 + (lane & 15);
    int kq = (lane >> 4) * 8;

    // prologue: stage first K-step into buf 0
    {
        unsigned short* a = &As[0][w * 1024];
        unsigned short* b = &Bs[0][w * 1024];
        GLOAD16(gA0 + k_lo, a);
        GLOAD16(gA1 + k_lo, a + 512);
        GLOAD16(gB0 + k_lo, b);
        GLOAD16(gB1 + k_lo, b + 512);
    }
    int cur = 0;

    for (int kt = k_lo; kt < k_hi; kt += BK) {
        // __syncthreads drains vmcnt(0): buf[cur] staged; all waves off buf[cur^1]
        __syncthreads();

        if (kt + BK < k_hi) {
            unsigned short* a = &As[cur ^ 1][w * 1024];
            unsigned short* b = &Bs[cur ^ 1][w * 1024];
            GLOAD16(gA0 + kt + BK, a);
            GLOAD16(gA1 + kt + BK, a + 512);
            GLOAD16(gB0 + kt + BK, b);
            GLOAD16(gB1 + kt + BK, b + 512);
        }

        bf16x8 af[4], bfr[4];
#pragma unroll
        for (int mi = 0; mi < 4; ++mi)
            af[mi] = *reinterpret_cast<const bf16x8*>(&As[cur][(arow + mi * 16) * BK + kq]);
#pragma unroll
        for (int ni = 0; ni < 4; ++ni)
            bfr[ni] = *reinterpret_cast<const bf16x8*>(&Bs[cur][(brow + ni * 16) * BK + kq]);
#pragma unroll
        for (int mi = 0; mi < 4; ++mi)
#pragma unroll
            for (int ni = 0; ni < 4; ++ni)
                acc[mi][ni] = __builtin_amdgcn_mfma_f32_16x16x32_bf16(af[mi], bfr[ni], acc[mi][ni], 0, 0, 0);

        cur ^= 1;
    }

    // epilogue: C/D layout col = lane&15, row = (lane>>4)*4 + reg
    int crow0 = bi * 128 + wr * 64 + (lane >> 4) * 4;
    int ccol0 = bj * 128 + wc * 64 + (lane & 15);
    if (multi) {
#pragma unroll
        for (int mi = 0; mi < 4; ++mi)
#pragma unroll
            for (int ni = 0; ni < 4; ++ni) {
                float* cp = C + (size_t)(crow0 + mi * 16) * NN + ccol0 + ni * 16;
#pragma unroll
                for (int r2 = 0; r2 < 4; ++r2)
                    atomicAdd(&cp[(size_t)r2 * NN], acc[mi][ni][r2]);
            }
    } else {
#pragma unroll
        for (int mi = 0; mi < 4; ++mi)
#pragma unroll
            for (int ni = 0; ni < 4; ++ni) {
                float* cp = C + (size_t)(crow0 + mi * 16) * NN + ccol0 + ni * 16;
#pragma unroll
                for (int r2 = 0; r2 < 4; ++r2)
                    cp[(size_t)r2 * NN] = acc[mi][ni][r2];
            }
    }
}

extern "C" void kernel_launch(void* const* d_in, const int* in_sizes, int n_in,
                              void* d_out, int out_size, void* d_ws, size_t ws_size,
                              hipStream_t stream) {
    const float* A = (const float*)d_in[0];
    const float* B = (const float*)d_in[1];
    float* C = (float*)d_out;
    unsigned short* Ab = (unsigned short*)d_ws;            // 32 MB bf16 A (lower tiles valid)
    unsigned short* Bt = Ab + (size_t)NN * NN;             // 32 MB bf16 B^T (needed tiles valid)
    prep<<<PGRID, 256, 0, stream>>>(A, B, Ab, Bt, C);
    trimm<<<TGRID, 256, 0, stream>>>(Ab, Bt, C);
}

// Round 5
// 88.678 us; speedup vs baseline: 1.4643x; 1.4643x over previous
//
#include <hip/hip_runtime.h>
#include <stdint.h>

#define NN 4096
#define NB 32          // NN / 128
#define BK 32          // K-step (one 16x16x32 MFMA per step)

// trimm grid layout: [0,272) heavy half-units (d>=16), [272,664) light tiles
// (d<=15), [664,1160) strict-upper zero tiles.
#define NHUNITS 272
#define ZBASE 664
#define TGRID 1160

// prep grid: [0,4096) A rows, [4096,8192) B 64x64 subtiles, [8192,8328) heavy-C zero
#define PGRID 8328

typedef __bf16 bf16x8 __attribute__((ext_vector_type(8)));
typedef float f32x4 __attribute__((ext_vector_type(4)));
typedef unsigned short ushort8 __attribute__((ext_vector_type(8)));

// RTNE fp32 -> bf16
__device__ __forceinline__ unsigned short f2bf(float x) {
    union { float f; unsigned int u; } v; v.f = x;
    unsigned int u = v.u;
    u += 0x7fffu + ((u >> 16) & 1u);
    return (unsigned short)(u >> 16);
}

// async global->LDS, 16B per lane; LDS dest is wave-uniform base + lane*16
#define GLOAD16(g, l) __builtin_amdgcn_global_load_lds( \
    (const __attribute__((address_space(1))) unsigned int*)(g), \
    (__attribute__((address_space(3))) unsigned int*)(l), 16, 0, 0)

// heavy tile index h (0..135) -> (bi,bj), d descending from 31 to 16
__device__ __forceinline__ void heavy_map(int h, int& bi, int& bj) {
    int t = h, d = NB - 1;
    while (t >= NB - d) { t -= NB - d; --d; }
    bj = t; bi = t + d;
}

// ---- fused prep: A lower-prefix convert, B lower transpose-convert, heavy-C zero ----
__global__ __launch_bounds__(256) void prep(const float* __restrict__ A,
                                            const float* __restrict__ B,
                                            unsigned short* __restrict__ Ab,
                                            unsigned short* __restrict__ Bt,
                                            float* __restrict__ C) {
    __shared__ float tile[64][65];
    int bid = blockIdx.x;
    int tid = threadIdx.x;

    if (bid < 4096) {
        // A row i: convert fp32 prefix [0, ((i>>7)+1)*128) to bf16
        int i = bid;
        int nslots = (((i >> 7) + 1) * 128) >> 3;   // 8 floats per slot
        const float4* src = reinterpret_cast<const float4*>(A + (size_t)i * NN);
        unsigned short* dst = Ab + (size_t)i * NN;
        for (int p = tid; p < nslots; p += 256) {
            float4 x0 = src[p * 2], x1 = src[p * 2 + 1];
            ushort8 o;
            o[0] = f2bf(x0.x); o[1] = f2bf(x0.y); o[2] = f2bf(x0.z); o[3] = f2bf(x0.w);
            o[4] = f2bf(x1.x); o[5] = f2bf(x1.y); o[6] = f2bf(x1.z); o[7] = f2bf(x1.w);
            *reinterpret_cast<ushort8*>(dst + p * 8) = o;
        }
        return;
    }
    if (bid < 8192) {
        // B 64x64 subtile transpose: needed iff k64 >= (n64 & ~1)  (128-tile lower superset)
        int s = bid - 4096;
        int n64 = s >> 6, k64 = s & 63;
        if (k64 < (n64 & ~1)) return;
        int n0 = n64 * 64, k0 = k64 * 64;
        int tx = tid & 63, ty = tid >> 6;
#pragma unroll
        for (int r = 0; r < 16; ++r) {
            int k = ty + r * 4;
            tile[k][tx] = B[(size_t)(k0 + k) * NN + n0 + tx];
        }
        __syncthreads();
#pragma unroll
        for (int r = 0; r < 16; ++r) {
            int n = ty + r * 4;
            Bt[(size_t)(n0 + n) * NN + k0 + tx] = f2bf(tile[tx][n]);
        }
        return;
    }
    // zero-init heavy C tile (atomicAdd targets; re-zeroed every call)
    int h = bid - 8192;
    int bi, bj; heavy_map(h, bi, bj);
    float4 z = make_float4(0.f, 0.f, 0.f, 0.f);
    float4* cp = reinterpret_cast<float4*>(C + (size_t)bi * 128 * NN + (size_t)bj * 128);
#pragma unroll
    for (int i2 = 0; i2 < 16; ++i2) {
        int slot = tid + i2 * 256;
        int row = slot >> 5, c4 = slot & 31;
        cp[(size_t)row * (NN / 4) + c4] = z;
    }
}

// ---- triangular GEMM, 2-way split-K heavy, 2-deep counted-vmcnt pipeline ----
__global__ __launch_bounds__(256) void trimm(const unsigned short* __restrict__ Ab,
                                             const unsigned short* __restrict__ Bt,
                                             float* __restrict__ C) {
    int bid = blockIdx.x;
    int tid = threadIdx.x;
    int lane = tid & 63;
    int w = tid >> 6;

    int bi, bj;
    bool heavy = false;
    int k_lo, k_hi;

    if (bid >= ZBASE) {
        // strict upper tile: zero-fill 128x128
        int t = bid - ZBASE;
        int r = 0, cnt = NB - 1;
        while (t >= cnt) { t -= cnt; ++r; --cnt; }
        bi = r; bj = r + 1 + t;
        float4 z = make_float4(0.f, 0.f, 0.f, 0.f);
        float4* cp = reinterpret_cast<float4*>(C + (size_t)bi * 128 * NN + (size_t)bj * 128);
#pragma unroll
        for (int i2 = 0; i2 < 16; ++i2) {
            int slot = tid + i2 * 256;
            int row = slot >> 5, c4 = slot & 31;
            cp[(size_t)row * (NN / 4) + c4] = z;
        }
        return;
    }
    if (bid < NHUNITS) {
        // heavy half-unit: tile h = bid>>1, K-half = bid&1
        heavy = true;
        int h = bid >> 1, half = bid & 1;
        heavy_map(h, bi, bj);
        k_lo = bj * 128;
        k_hi = (bi + 1) * 128;
        int len = (k_hi - k_lo) >> 1;      // multiple of 64 -> multiple of BK
        if (half == 0) k_hi = k_lo + len;
        else           k_lo = k_lo + len;
    } else {
        // light tile, d = 15..0 descending
        int t = bid - NHUNITS, d = 15;
        while (t >= NB - d) { t -= NB - d; --d; }
        bj = t; bi = t + d;
        k_lo = bj * 128;
        k_hi = (bi + 1) * 128;
    }

    __shared__ unsigned short As[2][128 * BK];
    __shared__ unsigned short Bs[2][128 * BK];

    int wr = w >> 1, wc = w & 1;

    // staging: LDS linear [row][4 x 16B-slot] per wave region; global source
    // pre-swizzled so LDS[row][slot] holds global k-chunk slot^((row>>1)&3).
    int srow = w * 32 + (lane >> 2);
    int skoff = (((lane & 3) ^ ((lane >> 3) & 3)) * 8);   // swizzled 16B chunk
    const unsigned short* gA0 = Ab + (size_t)(bi * 128 + srow) * NN + skoff;
    const unsigned short* gA1 = gA0 + (size_t)16 * NN;
    const unsigned short* gB0 = Bt + (size_t)(bj * 128 + srow) * NN + skoff;
    const unsigned short* gB1 = gB0 + (size_t)16 * NN;

    f32x4 acc[4][4];
#pragma unroll
    for (int mi = 0; mi < 4; ++mi)
#pragma unroll
        for (int ni = 0; ni < 4; ++ni)
            acc[mi][ni] = (f32x4){0.f, 0.f, 0.f, 0.f};

    int arow = wr * 64 + (lane & 15);
    int brow = wc * 64 + (lane & 15);
    // swizzled read slot: want chunk (lane>>4) of row R; stored at slot
    // (lane>>4)^((R>>1)&3); R mod 16 == lane&15 for all fragment rows.
    int kq = (((lane >> 4) ^ ((lane >> 1) & 3)) * 8);

#define STAGE(bufsel, kk) do { \
        unsigned short* a_ = &As[bufsel][w * 1024]; \
        unsigned short* b_ = &Bs[bufsel][w * 1024]; \
        GLOAD16(gA0 + (kk), a_); \
        GLOAD16(gA1 + (kk), a_ + 512); \
        GLOAD16(gB0 + (kk), b_); \
        GLOAD16(gB1 + (kk), b_ + 512); \
    } while (0)

    // prologue: stage steps t0 -> buf0, t1 -> buf1 (8 loads in flight)
    STAGE(0, k_lo);
    {
        int k1 = (k_lo + BK < k_hi) ? (k_lo + BK) : k_lo;
        STAGE(1, k1);
    }
    int cur = 0;

    for (int kt = k_lo; kt < k_hi; kt += BK) {
        // own 4 oldest loads (buf[cur]) landed; 4 newer may stay in flight
        asm volatile("s_waitcnt vmcnt(4)" ::: "memory");
        __builtin_amdgcn_s_barrier();   // all waves' buf[cur] loads visible

        bf16x8 af[4], bfr[4];
#pragma unroll
        for (int mi = 0; mi < 4; ++mi)
            af[mi] = *reinterpret_cast<const bf16x8*>(&As[cur][(arow + mi * 16) * BK + kq]);
#pragma unroll
        for (int ni = 0; ni < 4; ++ni)
            bfr[ni] = *reinterpret_cast<const bf16x8*>(&Bs[cur][(brow + ni * 16) * BK + kq]);
#pragma unroll
        for (int mi = 0; mi < 4; ++mi)
#pragma unroll
            for (int ni = 0; ni < 4; ++ni)
                acc[mi][ni] = __builtin_amdgcn_mfma_f32_16x16x32_bf16(af[mi], bfr[ni], acc[mi][ni], 0, 0, 0);

        __builtin_amdgcn_s_barrier();   // all waves done reading buf[cur]

        // stage step t+2 into buf[cur]; uniform dummy re-stage at tail keeps
        // per-wave vmcnt arithmetic constant (4 issued every iteration)
        int kn = kt + 2 * BK;
        if (kn >= k_hi) kn = k_lo;
        STAGE(cur, kn);

        cur ^= 1;
    }
    asm volatile("s_waitcnt vmcnt(0)" ::: "memory");  // drain dummies before endpgm
#undef STAGE

    // epilogue: C/D layout col = lane&15, row = (lane>>4)*4 + reg
    int crow0 = bi * 128 + wr * 64 + (lane >> 4) * 4;
    int ccol0 = bj * 128 + wc * 64 + (lane & 15);
    if (heavy) {
#pragma unroll
        for (int mi = 0; mi < 4; ++mi)
#pragma unroll
            for (int ni = 0; ni < 4; ++ni) {
                float* cp = C + (size_t)(crow0 + mi * 16) * NN + ccol0 + ni * 16;
#pragma unroll
                for (int r2 = 0; r2 < 4; ++r2)
                    atomicAdd(&cp[(size_t)r2 * NN], acc[mi][ni][r2]);
            }
    } else {
#pragma unroll
        for (int mi = 0; mi < 4; ++mi)
#pragma unroll
            for (int ni = 0; ni < 4; ++ni) {
                float* cp = C + (size_t)(crow0 + mi * 16) * NN + ccol0 + ni * 16;
#pragma unroll
                for (int r2 = 0; r2 < 4; ++r2)
                    cp[(size_t)r2 * NN] = acc[mi][ni][r2];
            }
    }
}

extern "C" void kernel_launch(void* const* d_in, const int* in_sizes, int n_in,
                              void* d_out, int out_size, void* d_ws, size_t ws_size,
                              hipStream_t stream) {
    const float* A = (const float*)d_in[0];
    const float* B = (const float*)d_in[1];
    float* C = (float*)d_out;
    unsigned short* Ab = (unsigned short*)d_ws;            // 32 MB bf16 A (lower tiles valid)
    unsigned short* Bt = Ab + (size_t)NN * NN;             // 32 MB bf16 B^T (needed tiles valid)
    prep<<<PGRID, 256, 0, stream>>>(A, B, Ab, Bt, C);
    trimm<<<TGRID, 256, 0, stream>>>(Ab, Bt, C);
}

// Round 6
// 88.476 us; speedup vs baseline: 1.4676x; 1.0023x over previous
//
#include <hip/hip_runtime.h>
#include <stdint.h>

#define NN 4096
#define NB 32          // NN / 128
#define BK 32          // K-step (one 16x16x32 MFMA per step)

// trimm grid layout: [0,272) heavy half-units (d>=16), [272,664) light tiles
// (d<=15), [664,1160) strict-upper zero tiles.
#define NHUNITS 272
#define ZBASE 664
#define TGRID 1160

// prep grid: [0,4096) A rows, [4096,8192) B 64x64 subtiles, [8192,8328) heavy-C zero
#define PGRID 8328

typedef __bf16 bf16x8 __attribute__((ext_vector_type(8)));
typedef float f32x4 __attribute__((ext_vector_type(4)));
typedef unsigned short ushort8 __attribute__((ext_vector_type(8)));

// RTNE fp32 -> bf16
__device__ __forceinline__ unsigned short f2bf(float x) {
    union { float f; unsigned int u; } v; v.f = x;
    unsigned int u = v.u;
    u += 0x7fffu + ((u >> 16) & 1u);
    return (unsigned short)(u >> 16);
}

// async global->LDS, 16B per lane; LDS dest is wave-uniform base + lane*16
#define GLOAD16(g, l) __builtin_amdgcn_global_load_lds( \
    (const __attribute__((address_space(1))) unsigned int*)(g), \
    (__attribute__((address_space(3))) unsigned int*)(l), 16, 0, 0)

// heavy tile index h (0..135) -> (bi,bj), d descending from 31 to 16
__device__ __forceinline__ void heavy_map(int h, int& bi, int& bj) {
    int t = h, d = NB - 1;
    while (t >= NB - d) { t -= NB - d; --d; }
    bj = t; bi = t + d;
}

// ---- fused prep: A lower-prefix convert, B lower transpose-convert, heavy-C zero ----
__global__ __launch_bounds__(256) void prep(const float* __restrict__ A,
                                            const float* __restrict__ B,
                                            unsigned short* __restrict__ Ab,
                                            unsigned short* __restrict__ Bt,
                                            float* __restrict__ C) {
    __shared__ float tile[64][65];
    int bid = blockIdx.x;
    int tid = threadIdx.x;

    if (bid < 4096) {
        // A row i: convert fp32 prefix [0, ((i>>7)+1)*128) to bf16
        int i = bid;
        int nslots = (((i >> 7) + 1) * 128) >> 3;   // 8 floats per slot
        const float4* src = reinterpret_cast<const float4*>(A + (size_t)i * NN);
        unsigned short* dst = Ab + (size_t)i * NN;
        for (int p = tid; p < nslots; p += 256) {
            float4 x0 = src[p * 2], x1 = src[p * 2 + 1];
            ushort8 o;
            o[0] = f2bf(x0.x); o[1] = f2bf(x0.y); o[2] = f2bf(x0.z); o[3] = f2bf(x0.w);
            o[4] = f2bf(x1.x); o[5] = f2bf(x1.y); o[6] = f2bf(x1.z); o[7] = f2bf(x1.w);
            *reinterpret_cast<ushort8*>(dst + p * 8) = o;
        }
        return;
    }
    if (bid < 8192) {
        // B 64x64 subtile transpose: needed iff k64 >= (n64 & ~1)  (128-tile lower superset)
        int s = bid - 4096;
        int n64 = s >> 6, k64 = s & 63;
        if (k64 < (n64 & ~1)) return;
        int n0 = n64 * 64, k0 = k64 * 64;
        int tx = tid & 63, ty = tid >> 6;
#pragma unroll
        for (int r = 0; r < 16; ++r) {
            int k = ty + r * 4;
            tile[k][tx] = B[(size_t)(k0 + k) * NN + n0 + tx];
        }
        __syncthreads();
#pragma unroll
        for (int r = 0; r < 16; ++r) {
            int n = ty + r * 4;
            Bt[(size_t)(n0 + n) * NN + k0 + tx] = f2bf(tile[tx][n]);
        }
        return;
    }
    // zero-init heavy C tile (atomicAdd targets; re-zeroed every call)
    int h = bid - 8192;
    int bi, bj; heavy_map(h, bi, bj);
    float4 z = make_float4(0.f, 0.f, 0.f, 0.f);
    float4* cp = reinterpret_cast<float4*>(C + (size_t)bi * 128 * NN + (size_t)bj * 128);
#pragma unroll
    for (int i2 = 0; i2 < 16; ++i2) {
        int slot = tid + i2 * 256;
        int row = slot >> 5, c4 = slot & 31;
        cp[(size_t)row * (NN / 4) + c4] = z;
    }
}

// ---- triangular GEMM, 2-way split-K heavy, 3-deep counted-vmcnt pipeline ----
__global__ __launch_bounds__(256) void trimm(const unsigned short* __restrict__ Ab,
                                             const unsigned short* __restrict__ Bt,
                                             float* __restrict__ C) {
    int bid = blockIdx.x;
    int tid = threadIdx.x;
    int lane = tid & 63;
    int w = tid >> 6;

    int bi, bj;
    bool heavy = false;
    int k_lo, k_hi;

    if (bid >= ZBASE) {
        // strict upper tile: zero-fill 128x128
        int t = bid - ZBASE;
        int r = 0, cnt = NB - 1;
        while (t >= cnt) { t -= cnt; ++r; --cnt; }
        bi = r; bj = r + 1 + t;
        float4 z = make_float4(0.f, 0.f, 0.f, 0.f);
        float4* cp = reinterpret_cast<float4*>(C + (size_t)bi * 128 * NN + (size_t)bj * 128);
#pragma unroll
        for (int i2 = 0; i2 < 16; ++i2) {
            int slot = tid + i2 * 256;
            int row = slot >> 5, c4 = slot & 31;
            cp[(size_t)row * (NN / 4) + c4] = z;
        }
        return;
    }
    if (bid < NHUNITS) {
        // heavy half-unit: tile h = bid>>1, K-half = bid&1
        heavy = true;
        int h = bid >> 1, half = bid & 1;
        heavy_map(h, bi, bj);
        k_lo = bj * 128;
        k_hi = (bi + 1) * 128;
        int len = (k_hi - k_lo) >> 1;      // multiple of 64 -> multiple of BK
        if (half == 0) k_hi = k_lo + len;
        else           k_lo = k_lo + len;
    } else {
        // light tile, d = 15..0 descending
        int t = bid - NHUNITS, d = 15;
        while (t >= NB - d) { t -= NB - d; --d; }
        bj = t; bi = t + d;
        k_lo = bj * 128;
        k_hi = (bi + 1) * 128;
    }

    __shared__ unsigned short As[3][128 * BK];
    __shared__ unsigned short Bs[3][128 * BK];

    int wr = w >> 1, wc = w & 1;

    // staging: LDS linear [row][4 x 16B-slot] per wave region; global source
    // pre-swizzled so LDS[row][slot] holds global k-chunk slot^((row>>1)&3).
    int srow = w * 32 + (lane >> 2);
    int skoff = (((lane & 3) ^ ((lane >> 3) & 3)) * 8);   // swizzled 16B chunk
    const unsigned short* gA0 = Ab + (size_t)(bi * 128 + srow) * NN + skoff;
    const unsigned short* gA1 = gA0 + (size_t)16 * NN;
    const unsigned short* gB0 = Bt + (size_t)(bj * 128 + srow) * NN + skoff;
    const unsigned short* gB1 = gB0 + (size_t)16 * NN;

    f32x4 acc[4][4];
#pragma unroll
    for (int mi = 0; mi < 4; ++mi)
#pragma unroll
        for (int ni = 0; ni < 4; ++ni)
            acc[mi][ni] = (f32x4){0.f, 0.f, 0.f, 0.f};

    int arow = wr * 64 + (lane & 15);
    int brow = wc * 64 + (lane & 15);
    // swizzled read slot: want chunk (lane>>4) of row R; stored at slot
    // (lane>>4)^((R>>1)&3); R mod 16 == lane&15 for all fragment rows.
    int kq = (((lane >> 4) ^ ((lane >> 1) & 3)) * 8);

#define STAGE(bufsel, kk) do { \
        unsigned short* a_ = &As[bufsel][w * 1024]; \
        unsigned short* b_ = &Bs[bufsel][w * 1024]; \
        GLOAD16(gA0 + (kk), a_); \
        GLOAD16(gA1 + (kk), a_ + 512); \
        GLOAD16(gB0 + (kk), b_); \
        GLOAD16(gB1 + (kk), b_ + 512); \
    } while (0)

    // prologue: stage steps t0,t1,t2 -> bufs 0,1,2 (12 loads in flight)
    STAGE(0, k_lo);
    {
        int k1 = (k_lo + BK < k_hi) ? (k_lo + BK) : k_lo;
        STAGE(1, k1);
        int k2 = (k_lo + 2 * BK < k_hi) ? (k_lo + 2 * BK) : k_lo;
        STAGE(2, k2);
    }
    int cur = 0;

    for (int kt = k_lo; kt < k_hi; kt += BK) {
        // own 4 oldest loads (buf[cur]) landed; 8 newer may stay in flight
        asm volatile("s_waitcnt vmcnt(8)" ::: "memory");
        __builtin_amdgcn_s_barrier();   // all waves' buf[cur] loads visible

        bf16x8 af[4], bfr[4];
#pragma unroll
        for (int mi = 0; mi < 4; ++mi)
            af[mi] = *reinterpret_cast<const bf16x8*>(&As[cur][(arow + mi * 16) * BK + kq]);
#pragma unroll
        for (int ni = 0; ni < 4; ++ni)
            bfr[ni] = *reinterpret_cast<const bf16x8*>(&Bs[cur][(brow + ni * 16) * BK + kq]);
#pragma unroll
        for (int mi = 0; mi < 4; ++mi)
#pragma unroll
            for (int ni = 0; ni < 4; ++ni)
                acc[mi][ni] = __builtin_amdgcn_mfma_f32_16x16x32_bf16(af[mi], bfr[ni], acc[mi][ni], 0, 0, 0);

        __builtin_amdgcn_s_barrier();   // all waves done reading buf[cur]

        // stage step t+3 into buf[cur]; uniform dummy re-stage at tail keeps
        // per-wave vmcnt arithmetic constant (4 issued every iteration)
        int kn = kt + 3 * BK;
        if (kn >= k_hi) kn = k_lo;
        STAGE(cur, kn);

        cur = (cur == 2) ? 0 : cur + 1;
    }
    asm volatile("s_waitcnt vmcnt(0)" ::: "memory");  // drain dummies before endpgm
#undef STAGE

    // epilogue: C/D layout col = lane&15, row = (lane>>4)*4 + reg
    int crow0 = bi * 128 + wr * 64 + (lane >> 4) * 4;
    int ccol0 = bj * 128 + wc * 64 + (lane & 15);
    if (heavy) {
#pragma unroll
        for (int mi = 0; mi < 4; ++mi)
#pragma unroll
            for (int ni = 0; ni < 4; ++ni) {
                float* cp = C + (size_t)(crow0 + mi * 16) * NN + ccol0 + ni * 16;
#pragma unroll
                for (int r2 = 0; r2 < 4; ++r2)
                    atomicAdd(&cp[(size_t)r2 * NN], acc[mi][ni][r2]);
            }
    } else {
#pragma unroll
        for (int mi = 0; mi < 4; ++mi)
#pragma unroll
            for (int ni = 0; ni < 4; ++ni) {
                float* cp = C + (size_t)(crow0 + mi * 16) * NN + ccol0 + ni * 16;
#pragma unroll
                for (int r2 = 0; r2 < 4; ++r2)
                    cp[(size_t)r2 * NN] = acc[mi][ni][r2];
            }
    }
}

extern "C" void kernel_launch(void* const* d_in, const int* in_sizes, int n_in,
                              void* d_out, int out_size, void* d_ws, size_t ws_size,
                              hipStream_t stream) {
    const float* A = (const float*)d_in[0];
    const float* B = (const float*)d_in[1];
    float* C = (float*)d_out;
    unsigned short* Ab = (unsigned short*)d_ws;            // 32 MB bf16 A (lower tiles valid)
    unsigned short* Bt = Ab + (size_t)NN * NN;             // 32 MB bf16 B^T (needed tiles valid)
    prep<<<PGRID, 256, 0, stream>>>(A, B, Ab, Bt, C);
    trimm<<<TGRID, 256, 0, stream>>>(Ab, Bt, C);
}

// Round 7
// 86.207 us; speedup vs baseline: 1.5063x; 1.0263x over previous
//
#include <hip/hip_runtime.h>
#include <stdint.h>

#define NN 4096
#define NB2 16         // NN / 256
#define BK2 64         // K-step (2 x 16x16x32 MFMA slots)

// trimm grid: [0,72) heavy half-units (d2>=8), [72,172) light tiles (d2<=7),
// [172,292) strict-upper 256^2 zero tiles.
#define NHUNITS 72
#define NUNITS 172
#define TGRID 292

// prep grid: [0,4096) A rows, [4096,8192) B 64x64 subtiles,
// [8192,8336) zero-init for split C tiles (36 tiles x 4 blocks)
#define PGRID 8336

typedef __bf16 bf16x8 __attribute__((ext_vector_type(8)));
typedef float f32x4 __attribute__((ext_vector_type(4)));
typedef unsigned short ushort8 __attribute__((ext_vector_type(8)));

// RTNE fp32 -> bf16
__device__ __forceinline__ unsigned short f2bf(float x) {
    union { float f; unsigned int u; } v; v.f = x;
    unsigned int u = v.u;
    u += 0x7fffu + ((u >> 16) & 1u);
    return (unsigned short)(u >> 16);
}

// async global->LDS, 16B per lane; LDS dest is wave-uniform base + lane*16
#define GLOAD16(g, l) __builtin_amdgcn_global_load_lds( \
    (const __attribute__((address_space(1))) unsigned int*)(g), \
    (__attribute__((address_space(3))) unsigned int*)(l), 16, 0, 0)

// split tile index z (0..35) -> (bi,bj), d2 descending 15..8
__device__ __forceinline__ void split_map(int z, int& bi, int& bj) {
    int d = 15;
    while (z >= NB2 - d) { z -= NB2 - d; --d; }
    bj = z; bi = z + d;
}

// ---- fused prep: A lower-prefix convert, B lower transpose-convert, split-C zero ----
__global__ __launch_bounds__(256) void prep(const float* __restrict__ A,
                                            const float* __restrict__ B,
                                            unsigned short* __restrict__ Ab,
                                            unsigned short* __restrict__ Bt,
                                            float* __restrict__ C) {
    __shared__ float tile[64][65];
    int bid = blockIdx.x;
    int tid = threadIdx.x;

    if (bid < 4096) {
        // A row i: convert fp32 prefix [0, ((i>>8)+1)*256) to bf16
        int i = bid;
        int nslots = ((i >> 8) + 1) * 32;   // 8 floats per slot
        const float4* src = reinterpret_cast<const float4*>(A + (size_t)i * NN);
        unsigned short* dst = Ab + (size_t)i * NN;
        for (int p = tid; p < nslots; p += 256) {
            float4 x0 = src[p * 2], x1 = src[p * 2 + 1];
            ushort8 o;
            o[0] = f2bf(x0.x); o[1] = f2bf(x0.y); o[2] = f2bf(x0.z); o[3] = f2bf(x0.w);
            o[4] = f2bf(x1.x); o[5] = f2bf(x1.y); o[6] = f2bf(x1.z); o[7] = f2bf(x1.w);
            *reinterpret_cast<ushort8*>(dst + p * 8) = o;
        }
        return;
    }
    if (bid < 8192) {
        // B 64x64 subtile transpose: needed iff k64 >= (n64 & ~3) (256-tile lower superset)
        int s = bid - 4096;
        int n64 = s >> 6, k64 = s & 63;
        if (k64 < (n64 & ~3)) return;
        int n0 = n64 * 64, k0 = k64 * 64;
        int tx = tid & 63, ty = tid >> 6;
#pragma unroll
        for (int r = 0; r < 16; ++r) {
            int k = ty + r * 4;
            tile[k][tx] = B[(size_t)(k0 + k) * NN + n0 + tx];
        }
        __syncthreads();
#pragma unroll
        for (int r = 0; r < 16; ++r) {
            int n = ty + r * 4;
            Bt[(size_t)(n0 + n) * NN + k0 + tx] = f2bf(tile[tx][n]);
        }
        return;
    }
    // zero-init split C tile (atomicAdd targets; re-zeroed every call)
    {
        int zb = bid - 8192;            // 0..143
        int bi, bj; split_map(zb >> 2, bi, bj);
        int part = zb & 3;              // 64-row stripe
        float4 zf = make_float4(0.f, 0.f, 0.f, 0.f);
        float4* cp = reinterpret_cast<float4*>(C + (size_t)(bi * 256 + part * 64) * NN + (size_t)bj * 256);
#pragma unroll
        for (int i2 = 0; i2 < 16; ++i2) {
            int slot = tid + i2 * 256;
            int row = slot >> 6, c4 = slot & 63;
            cp[(size_t)row * (NN / 4) + c4] = zf;
        }
    }
}

// ---- triangular GEMM: 256^2 tile, 8 waves, 4-quadrant phased schedule ----
__global__ __launch_bounds__(512, 2) void trimm(const unsigned short* __restrict__ Ab,
                                                const unsigned short* __restrict__ Bt,
                                                float* __restrict__ C) {
    int bid = blockIdx.x;
    int tid = threadIdx.x;
    int lane = tid & 63;
    int w = tid >> 6;          // 0..7

    if (bid >= NUNITS) {
        // strict upper 256^2 tile: zero-fill
        int r = bid - NUNITS, bi = 0;
        while (r >= NB2 - 1 - bi) { r -= NB2 - 1 - bi; ++bi; }
        int bj = bi + 1 + r;
        float4 z = make_float4(0.f, 0.f, 0.f, 0.f);
        float4* cp = reinterpret_cast<float4*>(C + (size_t)bi * 256 * NN + (size_t)bj * 256);
#pragma unroll
        for (int i2 = 0; i2 < 32; ++i2) {
            int slot = tid + i2 * 512;
            int row = slot >> 6, c4 = slot & 63;
            cp[(size_t)row * (NN / 4) + c4] = z;
        }
        return;
    }

    int bi, bj, k_lo, k_hi;
    bool atom;
    if (bid < NHUNITS) {
        // heavy half-unit (d2>=8): 2 units per tile
        atom = true;
        int r = bid, d = 15;
        while (r >= 2 * (NB2 - d)) { r -= 2 * (NB2 - d); --d; }
        int t = r >> 1, half = r & 1;
        bj = t; bi = t + d;
        int base = bj * 256, len = (d + 1) * 128;   // half-length, multiple of 64
        k_lo = base + (half ? len : 0);
        k_hi = k_lo + len;
    } else {
        // light tile (d2<=7), descending d2
        atom = false;
        int r = bid - NHUNITS, d = 7;
        while (r >= NB2 - d) { r -= NB2 - d; --d; }
        bj = r; bi = r + d;
        k_lo = bj * 256;
        k_hi = (bi + 1) * 256;
    }

    __shared__ unsigned short As[2][256 * 64];   // 64 KB
    __shared__ unsigned short Bs[2][256 * 64];   // 64 KB

    int wr = w >> 2;           // 0..1  (M half: 128 rows)
    int wc = w & 3;            // 0..3  (N quarter: 64 cols)

    // stage addressing: thread covers (row seg*64 + tid>>3, chunk tid&7);
    // global source pre-swizzled: chunk c_dest holds global chunk c_dest^(row&7)
    int srow = tid >> 3;
    int sgch = (tid & 7) ^ (srow & 7);
    const unsigned short* gAs = Ab + (size_t)(bi * 256 + srow) * NN + sgch * 8;
    const unsigned short* gBs = Bt + (size_t)(bj * 256 + srow) * NN + sgch * 8;

    // fragment read addressing (swizzled): for kslot s, chunk = (s*4 + lane>>4) ^ (lane&7)
    int fr = lane & 15;
    int ch0 = ((lane >> 4)) ^ (lane & 7);
    int ch1 = (4 | (lane >> 4)) ^ (lane & 7);

    f32x4 acc[8][4];
#pragma unroll
    for (int m = 0; m < 8; ++m)
#pragma unroll
        for (int n = 0; n < 4; ++n)
            acc[m][n] = (f32x4){0.f, 0.f, 0.f, 0.f};

    bf16x8 Aq[8], B0q[4], B1q[4];

#define STAGE(bufsel, kk) do { \
        unsigned short* la_ = &As[bufsel][0] + tid * 8; \
        unsigned short* lb_ = &Bs[bufsel][0] + tid * 8; \
        GLOAD16(gAs + (kk), la_); \
        GLOAD16(gAs + (kk) + 64 * NN, la_ + 4096); \
        GLOAD16(gAs + (kk) + 128 * NN, la_ + 8192); \
        GLOAD16(gAs + (kk) + 192 * NN, la_ + 12288); \
        GLOAD16(gBs + (kk), lb_); \
        GLOAD16(gBs + (kk) + 64 * NN, lb_ + 4096); \
        GLOAD16(gBs + (kk) + 128 * NN, lb_ + 8192); \
        GLOAD16(gBs + (kk) + 192 * NN, lb_ + 12288); \
    } while (0)

#define LDA(MH) do { \
        _Pragma("unroll") for (int m_ = 0; m_ < 4; ++m_) { \
            int row_ = wr * 128 + ((MH) * 4 + m_) * 16 + fr; \
            Aq[m_ * 2 + 0] = *reinterpret_cast<const bf16x8*>(&Ac[row_ * 64 + ch0 * 8]); \
            Aq[m_ * 2 + 1] = *reinterpret_cast<const bf16x8*>(&Ac[row_ * 64 + ch1 * 8]); \
        } \
    } while (0)

#define LDB(NH, BQ) do { \
        _Pragma("unroll") for (int n_ = 0; n_ < 2; ++n_) { \
            int row_ = wc * 64 + ((NH) * 2 + n_) * 16 + fr; \
            BQ[n_ * 2 + 0] = *reinterpret_cast<const bf16x8*>(&Bc[row_ * 64 + ch0 * 8]); \
            BQ[n_ * 2 + 1] = *reinterpret_cast<const bf16x8*>(&Bc[row_ * 64 + ch1 * 8]); \
        } \
    } while (0)

#define MFMA16(MB, NBASE, BQ) do { \
        _Pragma("unroll") for (int m_ = 0; m_ < 4; ++m_) \
        _Pragma("unroll") for (int n_ = 0; n_ < 2; ++n_) { \
            acc[(MB) + m_][(NBASE) + n_] = __builtin_amdgcn_mfma_f32_16x16x32_bf16( \
                Aq[m_ * 2 + 0], BQ[n_ * 2 + 0], acc[(MB) + m_][(NBASE) + n_], 0, 0, 0); \
            acc[(MB) + m_][(NBASE) + n_] = __builtin_amdgcn_mfma_f32_16x16x32_bf16( \
                Aq[m_ * 2 + 1], BQ[n_ * 2 + 1], acc[(MB) + m_][(NBASE) + n_], 0, 0, 0); \
        } \
    } while (0)

    int nt = (k_hi - k_lo) >> 6;

    // prologue: stage tile 0 -> buf0
    STAGE(0, k_lo);
    __syncthreads();

    for (int t = 0; t < nt; ++t) {
        int cur = t & 1;
        const unsigned short* Ac = &As[cur][0];
        const unsigned short* Bc = &Bs[cur][0];

        // PHASE 0: read A(M0) + B(N0); stage next tile into other buf; MFMA Q0
        LDA(0);
        LDB(0, B0q);
        if (t + 1 < nt) STAGE(cur ^ 1, k_lo + (t + 1) * BK2);
        __builtin_amdgcn_s_barrier();
        __builtin_amdgcn_s_setprio(1);
        MFMA16(0, 0, B0q);
        __builtin_amdgcn_s_setprio(0);
        __builtin_amdgcn_s_barrier();

        // PHASE 1: read B(N1); MFMA Q1 = M0 x N1
        LDB(1, B1q);
        __builtin_amdgcn_s_barrier();
        __builtin_amdgcn_s_setprio(1);
        MFMA16(0, 2, B1q);
        __builtin_amdgcn_s_setprio(0);
        __builtin_amdgcn_s_barrier();

        // PHASE 2: read A(M1); MFMA Q2 = M1 x N1
        LDA(1);
        __builtin_amdgcn_s_barrier();
        __builtin_amdgcn_s_setprio(1);
        MFMA16(4, 2, B1q);
        __builtin_amdgcn_s_setprio(0);
        __builtin_amdgcn_s_barrier();

        // PHASE 3: MFMA Q3 = M1 x N0; tile gate (vmcnt(0)+lgkm(0)+barrier)
        __builtin_amdgcn_s_setprio(1);
        MFMA16(4, 0, B0q);
        __builtin_amdgcn_s_setprio(0);
        __syncthreads();
    }
#undef STAGE
#undef LDA
#undef LDB
#undef MFMA16

    // epilogue: C/D layout col = lane&15, row = (lane>>4)*4 + reg
    int crow0 = bi * 256 + wr * 128 + (lane >> 4) * 4;
    int ccol0 = bj * 256 + wc * 64 + fr;
    if (atom) {
#pragma unroll
        for (int m = 0; m < 8; ++m)
#pragma unroll
            for (int n = 0; n < 4; ++n) {
                float* cp = C + (size_t)(crow0 + m * 16) * NN + ccol0 + n * 16;
#pragma unroll
                for (int r2 = 0; r2 < 4; ++r2)
                    atomicAdd(&cp[(size_t)r2 * NN], acc[m][n][r2]);
            }
    } else {
#pragma unroll
        for (int m = 0; m < 8; ++m)
#pragma unroll
            for (int n = 0; n < 4; ++n) {
                float* cp = C + (size_t)(crow0 + m * 16) * NN + ccol0 + n * 16;
#pragma unroll
                for (int r2 = 0; r2 < 4; ++r2)
                    cp[(size_t)r2 * NN] = acc[m][n][r2];
            }
    }
}

extern "C" void kernel_launch(void* const* d_in, const int* in_sizes, int n_in,
                              void* d_out, int out_size, void* d_ws, size_t ws_size,
                              hipStream_t stream) {
    const float* A = (const float*)d_in[0];
    const float* B = (const float*)d_in[1];
    float* C = (float*)d_out;
    unsigned short* Ab = (unsigned short*)d_ws;            // 32 MB bf16 A (lower tiles valid)
    unsigned short* Bt = Ab + (size_t)NN * NN;             // 32 MB bf16 B^T (needed tiles valid)
    prep<<<PGRID, 256, 0, stream>>>(A, B, Ab, Bt, C);
    trimm<<<TGRID, 512, 0, stream>>>(Ab, Bt, C);
}

// Round 8
// 75.681 us; speedup vs baseline: 1.7158x; 1.1391x over previous
//
#include <hip/hip_runtime.h>
#include <stdint.h>

#define NN 4096
#define NB 32          // NN / 128
#define BK 64          // K-step (2 x 16x16x32 MFMA k-slots)

// trimm grid layout: [0,272) heavy half-units (d>=16), [272,664) light tiles
// (d<=15), [664,1160) strict-upper zero tiles.
#define NHUNITS 272
#define ZBASE 664
#define TGRID 1160

// prep grid: [0,4096) A rows, [4096,8192) B 64x64 subtiles, [8192,8328) heavy-C zero
#define PGRID 8328

typedef __bf16 bf16x8 __attribute__((ext_vector_type(8)));
typedef float f32x4 __attribute__((ext_vector_type(4)));
typedef unsigned short ushort8 __attribute__((ext_vector_type(8)));

// RTNE fp32 -> bf16
__device__ __forceinline__ unsigned short f2bf(float x) {
    union { float f; unsigned int u; } v; v.f = x;
    unsigned int u = v.u;
    u += 0x7fffu + ((u >> 16) & 1u);
    return (unsigned short)(u >> 16);
}

// async global->LDS, 16B per lane; LDS dest is wave-uniform base + lane*16
#define GLOAD16(g, l) __builtin_amdgcn_global_load_lds( \
    (const __attribute__((address_space(1))) unsigned int*)(g), \
    (__attribute__((address_space(3))) unsigned int*)(l), 16, 0, 0)

// heavy tile index h (0..135) -> (bi,bj), d descending from 31 to 16
__device__ __forceinline__ void heavy_map(int h, int& bi, int& bj) {
    int t = h, d = NB - 1;
    while (t >= NB - d) { t -= NB - d; --d; }
    bj = t; bi = t + d;
}

// ---- fused prep: A lower-prefix convert, B lower transpose-convert, heavy-C zero ----
__global__ __launch_bounds__(256) void prep(const float* __restrict__ A,
                                            const float* __restrict__ B,
                                            unsigned short* __restrict__ Ab,
                                            unsigned short* __restrict__ Bt,
                                            float* __restrict__ C) {
    __shared__ float tile[64][65];
    int bid = blockIdx.x;
    int tid = threadIdx.x;

    if (bid < 4096) {
        // A row i: convert fp32 prefix [0, ((i>>7)+1)*128) to bf16
        int i = bid;
        int nslots = (((i >> 7) + 1) * 128) >> 3;   // 8 floats per slot
        const float4* src = reinterpret_cast<const float4*>(A + (size_t)i * NN);
        unsigned short* dst = Ab + (size_t)i * NN;
        for (int p = tid; p < nslots; p += 256) {
            float4 x0 = src[p * 2], x1 = src[p * 2 + 1];
            ushort8 o;
            o[0] = f2bf(x0.x); o[1] = f2bf(x0.y); o[2] = f2bf(x0.z); o[3] = f2bf(x0.w);
            o[4] = f2bf(x1.x); o[5] = f2bf(x1.y); o[6] = f2bf(x1.z); o[7] = f2bf(x1.w);
            *reinterpret_cast<ushort8*>(dst + p * 8) = o;
        }
        return;
    }
    if (bid < 8192) {
        // B 64x64 subtile transpose: needed iff k64 >= (n64 & ~1)  (128-tile lower superset)
        int s = bid - 4096;
        int n64 = s >> 6, k64 = s & 63;
        if (k64 < (n64 & ~1)) return;
        int n0 = n64 * 64, k0 = k64 * 64;
        int tx = tid & 63, ty = tid >> 6;
#pragma unroll
        for (int r = 0; r < 16; ++r) {
            int k = ty + r * 4;
            tile[k][tx] = B[(size_t)(k0 + k) * NN + n0 + tx];
        }
        __syncthreads();
#pragma unroll
        for (int r = 0; r < 16; ++r) {
            int n = ty + r * 4;
            Bt[(size_t)(n0 + n) * NN + k0 + tx] = f2bf(tile[tx][n]);
        }
        return;
    }
    // zero-init heavy C tile (atomicAdd targets; re-zeroed every call)
    int h = bid - 8192;
    int bi, bj; heavy_map(h, bi, bj);
    float4 z = make_float4(0.f, 0.f, 0.f, 0.f);
    float4* cp = reinterpret_cast<float4*>(C + (size_t)bi * 128 * NN + (size_t)bj * 128);
#pragma unroll
    for (int i2 = 0; i2 < 16; ++i2) {
        int slot = tid + i2 * 256;
        int row = slot >> 5, c4 = slot & 31;
        cp[(size_t)row * (NN / 4) + c4] = z;
    }
}

// ---- triangular GEMM: 128^2 tile, BK=64, 2 blocks/CU, counted-vmcnt 2-deep ----
__global__ __launch_bounds__(256, 2) void trimm(const unsigned short* __restrict__ Ab,
                                                const unsigned short* __restrict__ Bt,
                                                float* __restrict__ C) {
    int bid = blockIdx.x;
    int tid = threadIdx.x;
    int lane = tid & 63;
    int w = tid >> 6;

    int bi, bj;
    bool heavy = false;
    int k_lo, k_hi;

    if (bid >= ZBASE) {
        // strict upper tile: zero-fill 128x128
        int t = bid - ZBASE;
        int r = 0, cnt = NB - 1;
        while (t >= cnt) { t -= cnt; ++r; --cnt; }
        bi = r; bj = r + 1 + t;
        float4 z = make_float4(0.f, 0.f, 0.f, 0.f);
        float4* cp = reinterpret_cast<float4*>(C + (size_t)bi * 128 * NN + (size_t)bj * 128);
#pragma unroll
        for (int i2 = 0; i2 < 16; ++i2) {
            int slot = tid + i2 * 256;
            int row = slot >> 5, c4 = slot & 31;
            cp[(size_t)row * (NN / 4) + c4] = z;
        }
        return;
    }
    if (bid < NHUNITS) {
        // heavy half-unit: tile h = bid>>1, K-half = bid&1
        heavy = true;
        int h = bid >> 1, half = bid & 1;
        heavy_map(h, bi, bj);
        k_lo = bj * 128;
        k_hi = (bi + 1) * 128;
        int len = (k_hi - k_lo) >> 1;      // (d+1)*64 -> multiple of BK
        if (half == 0) k_hi = k_lo + len;
        else           k_lo = k_lo + len;
    } else {
        // light tile, d = 15..0 descending
        int t = bid - NHUNITS, d = 15;
        while (t >= NB - d) { t -= NB - d; --d; }
        bj = t; bi = t + d;
        k_lo = bj * 128;
        k_hi = (bi + 1) * 128;
    }

    __shared__ unsigned short As[2][128 * BK];   // 2 x 16 KB
    __shared__ unsigned short Bs[2][128 * BK];   // 2 x 16 KB  (64 KB total -> 2 blocks/CU)

    int wr = w >> 1, wc = w & 1;

    // staging: LDS linear [row][8 x 16B-chunk]; source pre-swizzled so stored
    // chunk c of row r holds global chunk c^(r&7). Thread t covers rows
    // g*32 + (t>>3), chunk t&7, g=0..3 (per matrix).
    int srow = tid >> 3;
    int schunk = ((tid & 7) ^ (srow & 7)) * 8;
    const unsigned short* gA = Ab + (size_t)(bi * 128 + srow) * NN + schunk;
    const unsigned short* gB = Bt + (size_t)(bj * 128 + srow) * NN + schunk;

    f32x4 acc[4][4];
#pragma unroll
    for (int mi = 0; mi < 4; ++mi)
#pragma unroll
        for (int ni = 0; ni < 4; ++ni)
            acc[mi][ni] = (f32x4){0.f, 0.f, 0.f, 0.f};

    // fragment reads: row = (wr|wc)*64 + m*16 + (lane&15); want global chunk
    // (lane>>4) [kslot0] / 4+(lane>>4) [kslot1]; stored at chunk^(row&7),
    // row&7 == lane&7.
    int fr = lane & 15;
    int c0 = (((lane >> 4) ^ (lane & 7)) * 8);
    int c1 = ((((lane >> 4) | 4) ^ (lane & 7)) * 8);
    int arow = wr * 64 + fr;
    int brow = wc * 64 + fr;

#define STAGE(bufsel, kk) do { \
        unsigned short* la_ = &As[bufsel][0] + tid * 8; \
        unsigned short* lb_ = &Bs[bufsel][0] + tid * 8; \
        GLOAD16(gA + (kk), la_); \
        GLOAD16(gA + (kk) + (size_t)32 * NN, la_ + 2048); \
        GLOAD16(gA + (kk) + (size_t)64 * NN, la_ + 4096); \
        GLOAD16(gA + (kk) + (size_t)96 * NN, la_ + 6144); \
        GLOAD16(gB + (kk), lb_); \
        GLOAD16(gB + (kk) + (size_t)32 * NN, lb_ + 2048); \
        GLOAD16(gB + (kk) + (size_t)64 * NN, lb_ + 4096); \
        GLOAD16(gB + (kk) + (size_t)96 * NN, lb_ + 6144); \
    } while (0)

    int nt = (k_hi - k_lo) >> 6;   // >= 2 always

    // prologue: 2-deep (16 loads in flight)
    STAGE(0, k_lo);
    STAGE(1, k_lo + BK);
    int cur = 0;

    for (int t = 0; t < nt; ++t) {
        // own 8 oldest loads (buf[cur]) landed; 8 newer may stay in flight
        asm volatile("s_waitcnt vmcnt(8)" ::: "memory");
        __builtin_amdgcn_s_barrier();   // all waves' buf[cur] loads visible

        const unsigned short* Ac = &As[cur][0];
        const unsigned short* Bc = &Bs[cur][0];
        bf16x8 a0[4], a1[4], b0[4], b1[4];
#pragma unroll
        for (int m = 0; m < 4; ++m) {
            a0[m] = *reinterpret_cast<const bf16x8*>(&Ac[(arow + m * 16) * BK + c0]);
            a1[m] = *reinterpret_cast<const bf16x8*>(&Ac[(arow + m * 16) * BK + c1]);
        }
#pragma unroll
        for (int n = 0; n < 4; ++n) {
            b0[n] = *reinterpret_cast<const bf16x8*>(&Bc[(brow + n * 16) * BK + c0]);
            b1[n] = *reinterpret_cast<const bf16x8*>(&Bc[(brow + n * 16) * BK + c1]);
        }
#pragma unroll
        for (int m = 0; m < 4; ++m)
#pragma unroll
            for (int n = 0; n < 4; ++n) {
                acc[m][n] = __builtin_amdgcn_mfma_f32_16x16x32_bf16(a0[m], b0[n], acc[m][n], 0, 0, 0);
                acc[m][n] = __builtin_amdgcn_mfma_f32_16x16x32_bf16(a1[m], b1[n], acc[m][n], 0, 0, 0);
            }

        __builtin_amdgcn_s_barrier();   // all waves done reading buf[cur]

        // stage tile t+2 into buf[cur]; uniform dummy re-stage at tail keeps
        // per-wave vmcnt arithmetic constant (8 issued every iteration)
        int kn = k_lo + (t + 2) * BK;
        if (kn >= k_hi) kn = k_lo;
        STAGE(cur, kn);

        cur ^= 1;
    }
    asm volatile("s_waitcnt vmcnt(0)" ::: "memory");  // drain dummies before LDS dealloc
#undef STAGE

    // epilogue: C/D layout col = lane&15, row = (lane>>4)*4 + reg
    int crow0 = bi * 128 + wr * 64 + (lane >> 4) * 4;
    int ccol0 = bj * 128 + wc * 64 + fr;
    if (heavy) {
#pragma unroll
        for (int mi = 0; mi < 4; ++mi)
#pragma unroll
            for (int ni = 0; ni < 4; ++ni) {
                float* cp = C + (size_t)(crow0 + mi * 16) * NN + ccol0 + ni * 16;
#pragma unroll
                for (int r2 = 0; r2 < 4; ++r2)
                    atomicAdd(&cp[(size_t)r2 * NN], acc[mi][ni][r2]);
            }
    } else {
#pragma unroll
        for (int mi = 0; mi < 4; ++mi)
#pragma unroll
            for (int ni = 0; ni < 4; ++ni) {
                float* cp = C + (size_t)(crow0 + mi * 16) * NN + ccol0 + ni * 16;
#pragma unroll
                for (int r2 = 0; r2 < 4; ++r2)
                    cp[(size_t)r2 * NN] = acc[mi][ni][r2];
            }
    }
}

extern "C" void kernel_launch(void* const* d_in, const int* in_sizes, int n_in,
                              void* d_out, int out_size, void* d_ws, size_t ws_size,
                              hipStream_t stream) {
    const float* A = (const float*)d_in[0];
    const float* B = (const float*)d_in[1];
    float* C = (float*)d_out;
    unsigned short* Ab = (unsigned short*)d_ws;            // 32 MB bf16 A (lower tiles valid)
    unsigned short* Bt = Ab + (size_t)NN * NN;             // 32 MB bf16 B^T (needed tiles valid)
    prep<<<PGRID, 256, 0, stream>>>(A, B, Ab, Bt, C);
    trimm<<<TGRID, 256, 0, stream>>>(Ab, Bt, C);
}